// Round 6
// baseline (1775.574 us; speedup 1.0000x reference)
//
#include <hip/hip_runtime.h>

// Problem constants (all inputs/outputs fp32, proven in round 3)
#define NN    8192   // nodes
#define FIN   256    // input features
#define UNITS 64
#define HEADS 4
#define CTOT  256    // HEADS*UNITS
#define CAP   256    // max edges/row (deg ~ Bin(8192,.004)+self: mean 34, sd 5.7)
#define PBLK  512    // projection tile jobs (128 row-tiles x 4 heads)

// ---------------------------------------------------------------------------
// Single fused kernel, dynamic job queue (deadlock-free under any dispatch
// order: proj jobs are claimed by whichever 512 blocks run first).
//   job <  PBLK : 64x64 VALU GEMM tile feats=X·W[h] + fused attention-vector
//                 dots -> s_self/s_neigh [n][4]; then threadfence + done++.
//   job >= PBLK : row i = job-PBLK. Scan A row (HBM), compact edges in LDS,
//                 spin-wait done==PBLK (acquire), per-head softmax, gather
//                 feats rows (LLC), ELU, store. Scan overlaps other blocks'
//                 proj AND other rows' gathers — HBM and LLC pipes overlap.
// ctrs[0] = job queue counter, ctrs[1] = proj-done counter (memset each call).
// ---------------------------------------------------------------------------
__global__ __launch_bounds__(256, 4) void k_fused(const float* __restrict__ X,
                                                  const float* __restrict__ W,
                                                  const float* __restrict__ atts,
                                                  const float* __restrict__ attn,
                                                  const float* __restrict__ A,
                                                  float* __restrict__ feats,
                                                  float* __restrict__ s_self,
                                                  float* __restrict__ s_neigh,
                                                  float* __restrict__ out,
                                                  int*   __restrict__ ctrs) {
    __shared__ __align__(16) char lds[17920];   // union of both paths
    __shared__ int jobS;
    __shared__ int cnt;
    const int tid = threadIdx.x;

    if (tid == 0) jobS = atomicAdd(&ctrs[0], 1);
    __syncthreads();
    const int job = jobS;

    if (job < PBLK) {
        // ===================== projection GEMM tile =====================
        float* Xt   = (float*)lds;          // [k][row], stride 68 -> 8704 B
        float* Wl   = Xt + 32 * 68;         // [k][u] -> 8704 B
        float* reds = Wl + 32 * 68;         // 64 floats
        float* redn = reds + 64;            // 64 floats
        const int rt = job & 127;           // row tile
        const int h  = job >> 7;            // head
        const int r0 = rt * 64;

        const int r  = (tid & 15) * 4;      // micro-tile row base
        const int cl = (tid >> 4) * 4;      // micro-tile col base
        const int srow = tid >> 2;          // 0..63
        const int skq  = (tid & 3) * 8;     // 0,8,16,24
        const int wk   = tid >> 3;          // 0..31
        const int wu   = (tid & 7) * 8;     // 0..56

        if (tid < 64) { reds[tid] = 0.f; redn[tid] = 0.f; }

        float acc[4][4];
        #pragma unroll
        for (int a = 0; a < 4; ++a)
            #pragma unroll
            for (int b = 0; b < 4; ++b) acc[a][b] = 0.f;

        for (int k0 = 0; k0 < FIN; k0 += 32) {
            __syncthreads();
            {
                const float4* xp = reinterpret_cast<const float4*>(
                    X + (size_t)(r0 + srow) * FIN + k0 + skq);
                const float4 x0 = xp[0], x1 = xp[1];
                const float xs[8] = {x0.x, x0.y, x0.z, x0.w, x1.x, x1.y, x1.z, x1.w};
                #pragma unroll
                for (int m = 0; m < 8; ++m) Xt[(skq + m) * 68 + srow] = xs[m];
            }
            {
                const float4* wp = reinterpret_cast<const float4*>(
                    W + (size_t)h * (FIN * UNITS) + (size_t)(k0 + wk) * UNITS + wu);
                const float4 w0 = wp[0], w1 = wp[1];
                const float ws8[8] = {w0.x, w0.y, w0.z, w0.w, w1.x, w1.y, w1.z, w1.w};
                #pragma unroll
                for (int m = 0; m < 8; ++m) Wl[wk * 68 + wu + m] = ws8[m];
            }
            __syncthreads();
            #pragma unroll 8
            for (int k = 0; k < 32; ++k) {
                const float4 a4 = *reinterpret_cast<const float4*>(&Xt[k * 68 + r]);
                const float4 b4 = *reinterpret_cast<const float4*>(&Wl[k * 68 + cl]);
                const float av[4] = {a4.x, a4.y, a4.z, a4.w};
                const float bv[4] = {b4.x, b4.y, b4.z, b4.w};
                #pragma unroll
                for (int ri = 0; ri < 4; ++ri)
                    #pragma unroll
                    for (int ci = 0; ci < 4; ++ci)
                        acc[ri][ci] += av[ri] * bv[ci];
            }
        }

        float as4[4], an4[4];
        #pragma unroll
        for (int ci = 0; ci < 4; ++ci) {
            as4[ci] = atts[h * UNITS + cl + ci];
            an4[ci] = attn[h * UNITS + cl + ci];
        }
        #pragma unroll
        for (int ri = 0; ri < 4; ++ri) {
            float4 o = make_float4(acc[ri][0], acc[ri][1], acc[ri][2], acc[ri][3]);
            *reinterpret_cast<float4*>(
                &feats[(size_t)(r0 + r + ri) * CTOT + h * UNITS + cl]) = o;
            const float ps = acc[ri][0] * as4[0] + acc[ri][1] * as4[1]
                           + acc[ri][2] * as4[2] + acc[ri][3] * as4[3];
            const float pn = acc[ri][0] * an4[0] + acc[ri][1] * an4[1]
                           + acc[ri][2] * an4[2] + acc[ri][3] * an4[3];
            atomicAdd(&reds[r + ri], ps);   // LDS ds_add, 16-way per row
            atomicAdd(&redn[r + ri], pn);
        }
        __syncthreads();
        if (tid < 64) {
            s_self [((size_t)(r0 + tid) << 2) + h] = reds[tid];  // [n][4]
            s_neigh[((size_t)(r0 + tid) << 2) + h] = redn[tid];
        }
        // publish: make feats/s_* visible device-wide, then signal
        __threadfence();
        __syncthreads();
        if (tid == 0) __hip_atomic_fetch_add(&ctrs[1], 1, __ATOMIC_RELEASE,
                                             __HIP_MEMORY_SCOPE_AGENT);
        return;
    }

    // ========================= row job =========================
    int*  ej = (int*)lds;                         // CAP ints
    float (*sc)[CAP] = (float(*)[CAP])(lds + CAP * 4);   // [HEADS][CAP]
    const int i = job - PBLK;
    if (tid == 0) cnt = 0;
    __syncthreads();

    // ---- phase 1: scan A row (HBM), compact nonzero columns ----
    {
        const float4* Arow4 = reinterpret_cast<const float4*>(A + (size_t)i * NN);
        unsigned mask = 0;
        #pragma unroll
        for (int q = 0; q < 8; ++q) {             // 1 KB/wave/instr, coalesced
            const float4 v = Arow4[q * 256 + tid];
            mask |= (v.x != 0.f ? 1u : 0u) << (4 * q);
            mask |= (v.y != 0.f ? 1u : 0u) << (4 * q + 1);
            mask |= (v.z != 0.f ? 1u : 0u) << (4 * q + 2);
            mask |= (v.w != 0.f ? 1u : 0u) << (4 * q + 3);
        }
        const int c = __popc(mask);
        int base = 0;
        if (c) base = atomicAdd(&cnt, c);
        while (mask) {
            const int b = __ffs(mask) - 1;
            mask &= mask - 1;
            if (base < CAP) ej[base] = (b >> 2) * 1024 + tid * 4 + (b & 3);
            ++base;
        }
    }
    __syncthreads();
    const int ne = min(cnt, CAP);

    // ---- wait for all projection tiles (acquire) ----
    if (tid == 0) {
        while (__hip_atomic_load(&ctrs[1], __ATOMIC_ACQUIRE,
                                 __HIP_MEMORY_SCOPE_AGENT) < PBLK)
            __builtin_amdgcn_s_sleep(8);
    }
    __syncthreads();
    __threadfence();

    // ---- phase 2: per-head softmax over edges (wave w == head w) ----
    const int w    = tid >> 6;
    const int lane = tid & 63;
    const float si = s_self[((size_t)i << 2) + w];
    float m = -3.0e38f;
    for (int jj = lane; jj < ne; jj += 64) {
        const int j = ej[jj];
        float e = si + s_neigh[((size_t)j << 2) + w];
        e = (e > 0.f) ? e : 0.2f * e;             // leaky-relu(0.2)
        sc[w][jj] = e;
        m = fmaxf(m, e);
    }
    #pragma unroll
    for (int off = 32; off > 0; off >>= 1) m = fmaxf(m, __shfl_xor(m, off, 64));
    float l = 0.f;
    for (int jj = lane; jj < ne; jj += 64) {
        const float p = __expf(sc[w][jj] - m);
        sc[w][jj] = p;
        l += p;
    }
    #pragma unroll
    for (int off = 32; off > 0; off >>= 1) l += __shfl_xor(l, off, 64);
    const float rl = 1.f / l;                     // ne>=1 (self-loop)

    // ---- phase 3: weighted feats gather (LLC), x4 unrolled ----
    const float* fb = feats + tid;                // thread = (head w, unit lane)
    float o0 = 0.f, o1 = 0.f, o2 = 0.f, o3 = 0.f;
    int jj = 0;
    for (; jj + 4 <= ne; jj += 4) {
        const int ja = ej[jj], jb = ej[jj + 1], jc = ej[jj + 2], jd = ej[jj + 3];
        const float pa = sc[w][jj],     pb = sc[w][jj + 1];
        const float pc = sc[w][jj + 2], pd = sc[w][jj + 3];
        o0 += pa * fb[(size_t)ja * CTOT];
        o1 += pb * fb[(size_t)jb * CTOT];
        o2 += pc * fb[(size_t)jc * CTOT];
        o3 += pd * fb[(size_t)jd * CTOT];
    }
    for (; jj < ne; ++jj) o0 += sc[w][jj] * fb[(size_t)ej[jj] * CTOT];
    const float o = ((o0 + o1) + (o2 + o3)) * rl;
    const float rr = (o > 0.f) ? o : (__expf(o) - 1.f);   // ELU, alpha=1
    out[(size_t)i * CTOT + tid] = rr;
}

// ---------------------------------------------------------------------------
extern "C" void kernel_launch(void* const* d_in, const int* in_sizes, int n_in,
                              void* d_out, int out_size, void* d_ws, size_t ws_size,
                              hipStream_t stream) {
    const float* X    = (const float*)d_in[0];
    const float* A    = (const float*)d_in[1];
    const float* W    = (const float*)d_in[2];
    const float* atts = (const float*)d_in[3];
    const float* attn = (const float*)d_in[4];

    float* feats   = (float*)d_ws;                       // NN*CTOT fp32 = 8 MB
    float* s_self  = feats  + (size_t)NN * CTOT;         // NN*4 fp32
    float* s_neigh = s_self + (size_t)NN * HEADS;        // NN*4 fp32
    int*   ctrs    = (int*)(s_neigh + (size_t)NN * HEADS);  // 2 ints

    hipMemsetAsync(ctrs, 0, 2 * sizeof(int), stream);    // job queue + done flag
    k_fused<<<PBLK + NN, 256, 0, stream>>>(X, W, atts, attn, A,
                                           feats, s_self, s_neigh,
                                           (float*)d_out, ctrs);
}

// Round 7
// 392.637 us; speedup vs baseline: 4.5222x; 4.5222x over previous
//
#include <hip/hip_runtime.h>

// Problem constants (all inputs/outputs fp32, proven in round 3)
#define NN    8192   // nodes
#define FIN   256    // input features
#define UNITS 64
#define HEADS 4
#define CTOT  256    // HEADS*UNITS
#define CAP   256    // max edges/row (deg ~ Bin(8192,.004)+self: mean 34, sd 5.7)
#define PBLK  512    // projection blocks (128 row-tiles x 4 heads)

// ---------------------------------------------------------------------------
// Kernel 1 — heterogeneous grid (round-5 structure, best measured 393 µs):
//   blocks [0, PBLK):     64x64-tile VALU GEMM feats = X·W[h] + fused
//                         attention-vector dots -> s_self/s_neigh [n][4]
//   blocks [PBLK, +NN):   scan A row (i = bid-PBLK), compact edge list to ws
// The GEMM is compute-bound and the scan is HBM-bound; co-residency across
// CUs overlaps them inside ONE kernel (no cross-block sync needed — round 6
// proved agent-scope spin-wait causes an L2-invalidate storm on 8-XCD CDNA4).
// ---------------------------------------------------------------------------
__global__ __launch_bounds__(256) void k_proj_scan(const float* __restrict__ X,
                                                   const float* __restrict__ W,
                                                   const float* __restrict__ atts,
                                                   const float* __restrict__ attn,
                                                   const float* __restrict__ A,
                                                   float* __restrict__ feats,
                                                   float* __restrict__ s_self,
                                                   float* __restrict__ s_neigh,
                                                   int*   __restrict__ ej_g,
                                                   int*   __restrict__ cnt_g) {
    const int tid = threadIdx.x;
    const int bid = blockIdx.x;

    if (bid >= PBLK) {
        // ================= A-row scan / edge compaction =================
        __shared__ int ej[CAP];
        __shared__ int cnt;
        const int i = bid - PBLK;
        if (tid == 0) cnt = 0;
        __syncthreads();
        {
            const float4* Arow4 = reinterpret_cast<const float4*>(A + (size_t)i * NN);
            unsigned mask = 0;
            #pragma unroll
            for (int q = 0; q < 8; ++q) {        // 1 KB/wave/instr, coalesced
                const float4 v = Arow4[q * 256 + tid];
                mask |= (v.x != 0.f ? 1u : 0u) << (4 * q);
                mask |= (v.y != 0.f ? 1u : 0u) << (4 * q + 1);
                mask |= (v.z != 0.f ? 1u : 0u) << (4 * q + 2);
                mask |= (v.w != 0.f ? 1u : 0u) << (4 * q + 3);
            }
            const int c = __popc(mask);
            int base = 0;
            if (c) base = atomicAdd(&cnt, c);
            while (mask) {
                const int b = __ffs(mask) - 1;
                mask &= mask - 1;
                if (base < CAP) ej[base] = (b >> 2) * 1024 + tid * 4 + (b & 3);
                ++base;
            }
        }
        __syncthreads();
        const int ne = min(cnt, CAP);
        if (tid < ne) ej_g[(size_t)i * CAP + tid] = ej[tid];
        if (tid == 0) cnt_g[i] = ne;
        return;
    }

    // ===================== projection GEMM (one head-tile) =====================
    __shared__ float Xt[32 * 68];   // [k][row], stride 68
    __shared__ float Wl[32 * 68];   // [k][u]
    __shared__ float reds[64];
    __shared__ float redn[64];
    const int rt = bid & 127;        // row tile
    const int h  = bid >> 7;         // head
    const int r0 = rt * 64;

    const int r  = (tid & 15) * 4;   // micro-tile row base
    const int cl = (tid >> 4) * 4;   // micro-tile col base
    const int srow = tid >> 2;       // 0..63
    const int skq  = (tid & 3) * 8;  // 0,8,16,24
    const int wk   = tid >> 3;       // 0..31
    const int wu   = (tid & 7) * 8;  // 0..56

    if (tid < 64) { reds[tid] = 0.f; redn[tid] = 0.f; }

    float acc[4][4];
    #pragma unroll
    for (int a = 0; a < 4; ++a)
        #pragma unroll
        for (int b = 0; b < 4; ++b) acc[a][b] = 0.f;

    for (int k0 = 0; k0 < FIN; k0 += 32) {
        __syncthreads();
        {
            const float4* xp = reinterpret_cast<const float4*>(
                X + (size_t)(r0 + srow) * FIN + k0 + skq);
            const float4 x0 = xp[0], x1 = xp[1];
            const float xs[8] = {x0.x, x0.y, x0.z, x0.w, x1.x, x1.y, x1.z, x1.w};
            #pragma unroll
            for (int m = 0; m < 8; ++m) Xt[(skq + m) * 68 + srow] = xs[m];
        }
        {
            const float4* wp = reinterpret_cast<const float4*>(
                W + (size_t)h * (FIN * UNITS) + (size_t)(k0 + wk) * UNITS + wu);
            const float4 w0 = wp[0], w1 = wp[1];
            const float ws8[8] = {w0.x, w0.y, w0.z, w0.w, w1.x, w1.y, w1.z, w1.w};
            #pragma unroll
            for (int m = 0; m < 8; ++m) Wl[wk * 68 + wu + m] = ws8[m];
        }
        __syncthreads();
        #pragma unroll 8
        for (int k = 0; k < 32; ++k) {
            const float4 a4 = *reinterpret_cast<const float4*>(&Xt[k * 68 + r]);
            const float4 b4 = *reinterpret_cast<const float4*>(&Wl[k * 68 + cl]);
            const float av[4] = {a4.x, a4.y, a4.z, a4.w};
            const float bv[4] = {b4.x, b4.y, b4.z, b4.w};
            #pragma unroll
            for (int ri = 0; ri < 4; ++ri)
                #pragma unroll
                for (int ci = 0; ci < 4; ++ci)
                    acc[ri][ci] += av[ri] * bv[ci];
        }
    }

    float as4[4], an4[4];
    #pragma unroll
    for (int ci = 0; ci < 4; ++ci) {
        as4[ci] = atts[h * UNITS + cl + ci];
        an4[ci] = attn[h * UNITS + cl + ci];
    }
    #pragma unroll
    for (int ri = 0; ri < 4; ++ri) {
        float4 o = make_float4(acc[ri][0], acc[ri][1], acc[ri][2], acc[ri][3]);
        *reinterpret_cast<float4*>(&feats[(size_t)(r0 + r + ri) * CTOT + h * UNITS + cl]) = o;
        const float ps = acc[ri][0] * as4[0] + acc[ri][1] * as4[1]
                       + acc[ri][2] * as4[2] + acc[ri][3] * as4[3];
        const float pn = acc[ri][0] * an4[0] + acc[ri][1] * an4[1]
                       + acc[ri][2] * an4[2] + acc[ri][3] * an4[3];
        atomicAdd(&reds[r + ri], ps);   // LDS ds_add, 16-way per row
        atomicAdd(&redn[r + ri], pn);
    }
    __syncthreads();
    if (tid < 64) {
        s_self [((size_t)(r0 + tid) << 2) + h] = reds[tid];  // [n][4]
        s_neigh[((size_t)(r0 + tid) << 2) + h] = redn[tid];
    }
}

// ---------------------------------------------------------------------------
// Kernel 2: per row i — load edge list, per-head (=per-wave) softmax,
// x4-unrolled weighted gather of feats rows (L2/LLC-resident), ELU, store.
// grid: 8192, block: 256
// ---------------------------------------------------------------------------
__global__ __launch_bounds__(256) void k_gat(const int*   __restrict__ ej_g,
                                             const int*   __restrict__ cnt_g,
                                             const float* __restrict__ feats,
                                             const float* __restrict__ s_self,
                                             const float* __restrict__ s_neigh,
                                             float* __restrict__ out) {
    __shared__ int   ej[CAP];
    __shared__ float sc[HEADS][CAP];
    const int tid = threadIdx.x;
    const int i   = blockIdx.x;
    const int ne  = cnt_g[i];
    if (tid < ne) ej[tid] = ej_g[(size_t)i * CAP + tid];
    __syncthreads();

    // ---- per-head softmax over edges (wave w == head w) ----
    const int w    = tid >> 6;
    const int lane = tid & 63;
    const float si = s_self[((size_t)i << 2) + w];
    float m = -3.0e38f;
    for (int jj = lane; jj < ne; jj += 64) {
        const int j = ej[jj];
        float e = si + s_neigh[((size_t)j << 2) + w];
        e = (e > 0.f) ? e : 0.2f * e;            // leaky-relu(0.2)
        sc[w][jj] = e;
        m = fmaxf(m, e);
    }
    #pragma unroll
    for (int off = 32; off > 0; off >>= 1) m = fmaxf(m, __shfl_xor(m, off, 64));
    float l = 0.f;
    for (int jj = lane; jj < ne; jj += 64) {
        const float p = __expf(sc[w][jj] - m);
        sc[w][jj] = p;
        l += p;
    }
    #pragma unroll
    for (int off = 32; off > 0; off >>= 1) l += __shfl_xor(l, off, 64);
    const float rl = 1.f / l;                    // ne>=1 (self-loop)

    // ---- weighted feats gather, x4 unrolled ----
    const float* fb = feats + tid;               // thread = (head w, unit lane)
    float o0 = 0.f, o1 = 0.f, o2 = 0.f, o3 = 0.f;
    int jj = 0;
    for (; jj + 4 <= ne; jj += 4) {
        const int ja = ej[jj], jb = ej[jj + 1], jc = ej[jj + 2], jd = ej[jj + 3];
        const float pa = sc[w][jj],     pb = sc[w][jj + 1];
        const float pc = sc[w][jj + 2], pd = sc[w][jj + 3];
        o0 += pa * fb[(size_t)ja * CTOT];
        o1 += pb * fb[(size_t)jb * CTOT];
        o2 += pc * fb[(size_t)jc * CTOT];
        o3 += pd * fb[(size_t)jd * CTOT];
    }
    for (; jj < ne; ++jj) o0 += sc[w][jj] * fb[(size_t)ej[jj] * CTOT];
    const float o = ((o0 + o1) + (o2 + o3)) * rl;
    const float rr = (o > 0.f) ? o : (__expf(o) - 1.f);   // ELU, alpha=1
    out[(size_t)i * CTOT + tid] = rr;
}

// ---------------------------------------------------------------------------
extern "C" void kernel_launch(void* const* d_in, const int* in_sizes, int n_in,
                              void* d_out, int out_size, void* d_ws, size_t ws_size,
                              hipStream_t stream) {
    const float* X    = (const float*)d_in[0];
    const float* A    = (const float*)d_in[1];
    const float* W    = (const float*)d_in[2];
    const float* atts = (const float*)d_in[3];
    const float* attn = (const float*)d_in[4];

    float* feats   = (float*)d_ws;                      // NN*CTOT fp32 = 8 MB
    float* s_self  = feats  + (size_t)NN * CTOT;        // NN*4 fp32
    float* s_neigh = s_self + (size_t)NN * HEADS;       // NN*4 fp32
    int*   cnt_g   = (int*)(s_neigh + (size_t)NN * HEADS);   // NN ints
    int*   ej_g    = cnt_g + NN;                        // NN*CAP ints = 8 MB

    k_proj_scan<<<PBLK + NN, 256, 0, stream>>>(X, W, atts, attn, A,
                                               feats, s_self, s_neigh, ej_g, cnt_g);
    k_gat<<<NN, 256, 0, stream>>>(ej_g, cnt_g, feats, s_self, s_neigh, (float*)d_out);
}